// Round 1
// 577.565 us; speedup vs baseline: 1.0100x; 1.0100x over previous
//
#include <hip/hip_runtime.h>
#include <math.h>
#include <stdint.h>

// CTC forward loss. B=128, T=128, C=6625, L=25, S=51. Output: 1 float.
//
// k_emit v2: ONE WAVE per (b,t) row (4 rows per 256-thread block).
//   - no LDS, no __syncthreads: butterfly __shfl_xor reduce within the wave.
//   - label gather x[c] is ISSUED BEFORE the streaming loop so its L2/L3
//     latency hides under the 26 float4 streaming iterations (even states
//     are blank=class 0, so c=0 preloads exactly the needed value).
//   - single-pass sum-of-exp (inputs N(0,1): no overflow; lse err ~1e-5
//     vs 2.1e-2 threshold). float4 loads with per-row alignment fixup
//     (row stride 6625 floats is only 4B-aligned).
//   - thread 0 of block 0 zeroes d_out (k_ctc accumulates atomically).
//
// k_ctc v2: one wave per batch element, lane = state. 127-step alpha
//   recursion. emit loads are software-pipelined 8 DEEP in named registers
//   (manual unroll-by-8; runtime-indexed arrays would spill to scratch):
//   ~8 loop bodies (~1200 cy) of slack covers a cross-XCD L3 miss, vs the
//   old 1-deep prefetch (~150 cy slack -> per-step stall).

#define NEGV (-1e30f)

constexpr int Bc = 128;
constexpr int Tc = 128;
constexpr int Cc = 6625;
constexpr int Lc = 25;
constexpr int Sc = 2 * Lc + 1;  // 51

__global__ __launch_bounds__(256) void k_emit(const float* __restrict__ predicts,
                                              const int* __restrict__ labels,
                                              float* __restrict__ emit,
                                              float* __restrict__ out) {
    if (blockIdx.x == 0 && threadIdx.x == 0) out[0] = 0.f;  // before k_ctc

    const int row = (blockIdx.x << 2) + (threadIdx.x >> 6);  // b*T + t
    const int lane = threadIdx.x & 63;
    const int b = row >> 7;  // T = 128
    const float* __restrict__ x = predicts + (size_t)row * Cc;

    // Early gather preload: even states are blank (c=0), odd states are
    // labels[b][s/2]. Issued now so the dependent-load latency hides under
    // the streaming loop below.
    int c = 0;
    if (lane < Sc && (lane & 1)) c = labels[b * Lc + (lane >> 1)];
    float xc = 0.f;
    if (lane < Sc) xc = x[c];

    // Alignment fixup: scalar prologue until 16B-aligned, float4 bulk, tail.
    const int mis = (int)(((uintptr_t)x >> 2) & 3);
    const int npro = (4 - mis) & 3;      // 0..3
    const int nvec = (Cc - npro) >> 2;   // 1655 or 1656
    const int ntail = (Cc - npro) & 3;   // 0..3
    const float4* __restrict__ xv = (const float4*)(x + npro);

    float ssum = 0.f;
    if (lane < npro) ssum += __expf(x[lane]);
    if (lane < ntail) ssum += __expf(x[npro + (nvec << 2) + lane]);

    // 25 unconditional iterations: max index 63 + 24*64 = 1599 < 1655.
#pragma unroll 5
    for (int k = 0; k < 25; ++k) {
        float4 v = xv[lane + (k << 6)];
        ssum += __expf(v.x) + __expf(v.y) + __expf(v.z) + __expf(v.w);
    }
    {   // final partial iteration: 1600..1663 vs nvec in {1655,1656}
        int j = lane + 1600;
        if (j < nvec) {
            float4 v = xv[j];
            ssum += __expf(v.x) + __expf(v.y) + __expf(v.z) + __expf(v.w);
        }
    }

#pragma unroll
    for (int off = 32; off; off >>= 1) ssum += __shfl_xor(ssum, off);
    const float lse = __logf(ssum);

    if (lane < Sc) emit[(size_t)row * Sc + lane] = xc - lse;
}

// One wave (64 lanes) per batch element; lane s = extended-label state s.
__global__ __launch_bounds__(64) void k_ctc(const float* __restrict__ emit,
                                            const int* __restrict__ labels,
                                            const int* __restrict__ lens,
                                            float* __restrict__ out) {
    const int b = blockIdx.x;
    const int s = threadIdx.x;  // 0..63, states 0..50 active

    const int ext = (s < Sc && (s & 1)) ? labels[b * Lc + (s >> 1)] : 0;
    const int ext_m2 = __shfl_up(ext, 2);
    const bool skip = (s >= 2) && (s < Sc) && (ext != ext_m2);

    const float* __restrict__ eb = emit + (size_t)b * Tc * Sc;
    const bool act = (s < Sc);

    float alpha = NEGV;
    if (s == 0) alpha = eb[0];
    else if (s == 1) alpha = eb[1];

    // Clamped load: prefetch for t >= T reads row 127 (discarded), never OOB.
#define LD(t) (act ? eb[((t) > Tc - 1 ? Tc - 1 : (t)) * Sc + s] : NEGV)
#define STEP(EV) do {                                                        \
        float a1 = __shfl_up(alpha, 1); if (s == 0) a1 = NEGV;               \
        float a2 = __shfl_up(alpha, 2); if (!skip) a2 = NEGV;                \
        float m = fmaxf(fmaxf(alpha, a1), a2);                               \
        alpha = m + __logf(__expf(alpha - m) + __expf(a1 - m) +              \
                           __expf(a2 - m)) + (EV);                           \
    } while (0)

    // 8-deep register pipeline over t = 1..127.
    float p0 = LD(1), p1 = LD(2), p2 = LD(3), p3 = LD(4);
    float p4 = LD(5), p5 = LD(6), p6 = LD(7), p7 = LD(8);

    int tb = 1;
    for (; tb + 7 < Tc; tb += 8) {  // 15 blocks: t = 1..120
        float q0 = LD(tb + 8),  q1 = LD(tb + 9),  q2 = LD(tb + 10), q3 = LD(tb + 11);
        float q4 = LD(tb + 12), q5 = LD(tb + 13), q6 = LD(tb + 14), q7 = LD(tb + 15);
        STEP(p0); STEP(p1); STEP(p2); STEP(p3);
        STEP(p4); STEP(p5); STEP(p6); STEP(p7);
        p0 = q0; p1 = q1; p2 = q2; p3 = q3;
        p4 = q4; p5 = q5; p6 = q6; p7 = q7;
    }
    // tail: t = 121..127 (7 steps), values already in p0..p6
    STEP(p0); STEP(p1); STEP(p2); STEP(p3); STEP(p4); STEP(p5); STEP(p6);

#undef LD
#undef STEP

    const int len = lens[b];
    const int idx = 2 * len;  // final blank position, <= 50
    const float ahi = __shfl(alpha, idx);
    const float alo = __shfl(alpha, idx - 1);
    if (s == 0) {
        float mm = fmaxf(ahi, alo);
        float ll = mm + __logf(__expf(ahi - mm) + __expf(alo - mm));
        float loss = -ll;
        if (loss > 1e29f) loss = 0.f;  // zero_infinity
        // mean over batch of loss/len, then the module divides by B again
        atomicAdd(out, loss / ((float)len * (float)Bc * (float)Bc));
    }
}

extern "C" void kernel_launch(void* const* d_in, const int* in_sizes, int n_in,
                              void* d_out, int out_size, void* d_ws, size_t ws_size,
                              hipStream_t stream) {
    const float* predicts = (const float*)d_in[0];
    const int* labels = (const int*)d_in[1];
    const int* lens = (const int*)d_in[2];
    float* out = (float*)d_out;
    float* emit = (float*)d_ws;  // B*T*S floats = ~3.3 MB

    k_emit<<<(Bc * Tc) / 4, 256, 0, stream>>>(predicts, labels, emit, out);
    k_ctc<<<Bc, 64, 0, stream>>>(emit, labels, lens, out);
}